// Round 4
// baseline (822.618 us; speedup 1.0000x reference)
//
#include <hip/hip_runtime.h>
#include <stdint.h>

// Problem constants
#define BB 128
#define SS 256
#define EE 1024
#define HH 16
#define DD 64
#define MM (BB*SS)   // 32768

#define LOG2E 1.44269504088896f

typedef __attribute__((ext_vector_type(8))) short bf16x8;
typedef __attribute__((ext_vector_type(4))) float f32x4;
typedef __attribute__((address_space(3))) unsigned short lds_us;

__device__ __forceinline__ unsigned short f2bf(float f) {
  union { float f; unsigned int u; } c; c.f = f;
  unsigned int u = c.u;
  u += 0x7fffu + ((u >> 16) & 1u);   // round-to-nearest-even
  return (unsigned short)(u >> 16);
}

__device__ __forceinline__ float fast_exp2(float x) {
#if __has_builtin(__builtin_amdgcn_exp2f)
  return __builtin_amdgcn_exp2f(x);
#else
  return exp2f(x);
#endif
}

__device__ __forceinline__ float fast_rcp(float x) {
#if __has_builtin(__builtin_amdgcn_rcpf)
  return __builtin_amdgcn_rcpf(x);
#else
  return 1.0f / x;
#endif
}

__device__ __forceinline__ void gld16(const unsigned short* g, unsigned short* l) {
  // async global->LDS, 16B/lane; LDS dest = wave-uniform base + lane*16
  __builtin_amdgcn_global_load_lds((__attribute__((address_space(1))) void*)(g),
                                   (__attribute__((address_space(3))) void*)(l), 16, 0, 0);
}

// inline-asm ds_read_b128: invisible to the compiler's LDS alias analysis, so
// SIInsertWaitcnts cannot insert vmcnt drains against global_load_lds staging.
// All waits are manual (lgkmcnt after barrier, counted vmcnt once per K-tile).
template <int OFF>
__device__ __forceinline__ bf16x8 dsr128(const lds_us* p) {
  bf16x8 r;
  asm volatile("ds_read_b128 %0, %1 offset:%2" : "=&v"(r) : "v"(p), "i"(OFF));
  return r;
}

// ---------------- merged prep: casts + bias layout build ----------------
__global__ __launch_bounds__(256) void prep_kernel(const float4* __restrict__ x4,
                                                   const float4* __restrict__ qw,
                                                   const float4* __restrict__ ow,
                                                   const float* __restrict__ btab,
                                                   const int* __restrict__ ridx,
                                                   ushort4* __restrict__ xb,
                                                   ushort4* __restrict__ qwb,
                                                   ushort4* __restrict__ owb,
                                                   float* __restrict__ biasC) {
  const int NX = (MM * EE) / 4;       // 8388608 float4
  const int NQ = (3 * EE * EE) / 4;   // 786432 float4
  const int NO = (EE * EE) / 4;       // 262144 float4
  const int NBIAS = HH * SS * SS;     // 1048576 floats
  const int total = NX + NQ + NO + NBIAS;   // 10485760
  int stride = gridDim.x * blockDim.x;
  for (int i = blockIdx.x * blockDim.x + threadIdx.x; i < total; i += stride) {
    if (i < NX) {
      float4 v = x4[i];
      ushort4 r; r.x = f2bf(v.x); r.y = f2bf(v.y); r.z = f2bf(v.z); r.w = f2bf(v.w);
      xb[i] = r;
    } else if (i < NX + NQ) {
      int t = i - NX;
      float4 v = qw[t];
      ushort4 r; r.x = f2bf(v.x); r.y = f2bf(v.y); r.z = f2bf(v.z); r.w = f2bf(v.w);
      qwb[t] = r;
    } else if (i < NX + NQ + NO) {
      int t = i - (NX + NQ);
      float4 v = ow[t];
      ushort4 r; r.x = f2bf(v.x); r.y = f2bf(v.y); r.z = f2bf(v.z); r.w = f2bf(v.w);
      owb[t] = r;
    } else {
      int t = i - (NX + NQ + NO);
      int h   = t >> 16;          // [H][row][lo][hi]
      int row = (t >> 8) & 255;
      int lo  = (t >> 4) & 15;
      int hi  = t & 15;
      int col = hi * 16 + lo;
      biasC[t] = btab[ridx[row * SS + col] * HH + h] * LOG2E;
    }
  }
}

// ---------------- 256x256 quadrant-major 8-phase GEMM mainloop (K=1024, BK=64) ----------------
// 512 threads = 8 waves (2 M x 4 N), per-wave C = 128x64 = 8x4 fragments.
// LDS: per matrix 2 dbuf x 2 k-half units of [256 rows][32 bf16] = 64KB; 128KB total.
// Phases per K-tile (t, buf d=t&1), each {asm ds_reads; stage; barrier; lgkm0; 16 MFMA; barrier}:
//   P1: af[mi0-3][kh0,1] (8) + bfr[nj0-1][kh0,1] (4) reads; stage B-k1(t+1) into buf d^1
//   P2: bfr[nj2-3][kh0,1] (4) reads; no stage
//   P3: af[mi4-7][kh0,1] (8) reads;  stage B-k0(t+2) (B(d,k0) read-done after P2)
//   P4: 0 reads; stage A-k0(t+2) + A-k1(t+2) (A(d,*) read-done after P3); counted vmcnt; 16 MFMA
// Steady state after P4's vmcnt(6): in flight = {A-k0(t+2),A-k1(t+2),B-k0(t+2)} = 6 loads;
// vmcnt(6) guarantees B-k1(t+1) and all older (incl. every tile t+1 unit) have landed.
#define GEMM_NT 16

__device__ __forceinline__ void mfma16(f32x4& c, bf16x8 a, bf16x8 b) {
  c = __builtin_amdgcn_mfma_f32_16x16x32_bf16(a, b, c, 0, 0, 0);
}

#define STAGE_A(buf, kh, tt) do { \
    unsigned short* _d = S_A + ((buf)*2 + (kh))*8192; \
    gld16(srcA0 + (tt)*64 + (kh)*32, _d + ldso0); \
    gld16(srcA1 + (tt)*64 + (kh)*32, _d + ldso1); } while (0)
#define STAGE_B(buf, kh, tt) do { \
    unsigned short* _d = S_B + ((buf)*2 + (kh))*8192; \
    gld16(srcB0 + (tt)*64 + (kh)*32, _d + ldso0); \
    gld16(srcB1 + (tt)*64 + (kh)*32, _d + ldso1); } while (0)

#define RAF(mi, kh, mbase) af[mi][kh] = dsr128<(kh)*16384 + ((mbase)+(mi))*1024>(aP)
#define RBF(nj, kh)        bfr[nj][kh] = dsr128<(kh)*16384 + (nj)*1024>(bP)

// 16 MFMA: one C-quadrant (4 mi x 2 nj) over full BK=64 (kh0+kh1).
// kh-outer so the two dependent MFMAs per acc are separated by 7 independent ones.
#define MF_Q(mi0, nj0) do { \
    _Pragma("unroll") for (int kh = 0; kh < 2; ++kh) \
    _Pragma("unroll") for (int mi = 0; mi < 4; ++mi) \
    _Pragma("unroll") for (int nj = 0; nj < 2; ++nj) \
      mfma16(acc[(mi0)+mi][(nj0)+nj], af[mi][kh], bfr[(nj0)+nj][kh]); } while (0)

#define BAR() __builtin_amdgcn_s_barrier()
#define WAITL0() do { asm volatile("s_waitcnt lgkmcnt(0)" ::: "memory"); \
                      __builtin_amdgcn_sched_barrier(0); } while (0)

__device__ __forceinline__ void gemm256_loop(const unsigned short* __restrict__ A,
                                             const unsigned short* __restrict__ Bw,
                                             unsigned short* S_A, unsigned short* S_B,
                                             int row0, int col0, f32x4 (&acc)[8][4]) {
  const int tid = threadIdx.x;
  const int wave = tid >> 6, lane = tid & 63;
  const int wm = wave >> 2, wn = wave & 3;
  const int l15 = lane & 15, quad = lane >> 4;
  // fragment read offsets (elements) within an 8192-element [256][32] unit
  const int cq = quad ^ ((l15 >> 1) & 3);                 // bank swizzle key (row bits 1-2)
  const int aoff = (wm * 128 + l15) * 32 + cq * 8;
  const int boff = (wn * 64 + l15) * 32 + cq * 8;
  // staging: lane li = g*512+tid covers row li>>2, LDS chunk li&3; global chunk swizzled
  const int r0g = tid >> 2, c0g = tid & 3;
  const int gc = c0g ^ ((r0g >> 1) & 3);                  // same key for g=0/1 (row+128)
  const unsigned short* srcA0 = A  + (size_t)(row0 + r0g) * EE + gc * 8;
  const unsigned short* srcA1 = A  + (size_t)(row0 + 128 + r0g) * EE + gc * 8;
  const unsigned short* srcB0 = Bw + (size_t)(col0 + r0g) * EE + gc * 8;
  const unsigned short* srcB1 = Bw + (size_t)(col0 + 128 + r0g) * EE + gc * 8;
  const int ldso0 = wave * 512;          // wave-uniform LDS element offsets
  const int ldso1 = 4096 + wave * 512;
  const lds_us* A3 = (const lds_us*)S_A;
  const lds_us* B3 = (const lds_us*)S_B;

  // prologue: tile0 (A0,B0,A1,B1) + tile1 (A0,A1,B0) = 14 loads; vmcnt(6) -> tile0 landed
  STAGE_A(0, 0, 0); STAGE_B(0, 0, 0); STAGE_A(0, 1, 0); STAGE_B(0, 1, 0);
  STAGE_A(1, 0, 1); STAGE_A(1, 1, 1); STAGE_B(1, 0, 1);
  asm volatile("s_waitcnt vmcnt(6)" ::: "memory");
  __builtin_amdgcn_sched_barrier(0);
  BAR();

  bf16x8 af[4][2], bfr[4][2];
  for (int t = 0; t < GEMM_NT; ++t) {
    const int d = t & 1;
    const lds_us* aP = A3 + (d << 14) + aoff;
    const lds_us* bP = B3 + (d << 14) + boff;
    // ---- P1: 12 reads; stage B-k1(t+1) into buf d^1 (that region read-done in group t-1 P2)
    RAF(0, 0, 0); RAF(1, 0, 0); RAF(2, 0, 0); RAF(3, 0, 0);
    RAF(0, 1, 0); RAF(1, 1, 0); RAF(2, 1, 0); RAF(3, 1, 0);
    RBF(0, 0); RBF(1, 0); RBF(0, 1); RBF(1, 1);
    if (t + 1 < GEMM_NT) STAGE_B(d ^ 1, 1, t + 1);
    asm volatile("s_waitcnt lgkmcnt(8)" ::: "memory");
    BAR();
    WAITL0();
    __builtin_amdgcn_s_setprio(1);
    MF_Q(0, 0);
    __builtin_amdgcn_s_setprio(0);
    BAR();
    // ---- P2: 4 reads (B nj2-3); no stage (A(d,*) still needed by P3)
    RBF(2, 0); RBF(3, 0); RBF(2, 1); RBF(3, 1);
    BAR();
    WAITL0();
    __builtin_amdgcn_s_setprio(1);
    MF_Q(0, 2);
    __builtin_amdgcn_s_setprio(0);
    BAR();
    // ---- P3: 8 reads (A mi4-7, overwrites af regs); stage B-k0(t+2) (B(d,k0) read-done after P2)
    RAF(0, 0, 4); RAF(1, 0, 4); RAF(2, 0, 4); RAF(3, 0, 4);
    RAF(0, 1, 4); RAF(1, 1, 4); RAF(2, 1, 4); RAF(3, 1, 4);
    if (t + 2 < GEMM_NT) STAGE_B(d, 0, t + 2);
    BAR();
    WAITL0();
    __builtin_amdgcn_s_setprio(1);
    MF_Q(4, 0);   // reuses bfr[0..1] from P1 (still live in regs)
    __builtin_amdgcn_s_setprio(0);
    BAR();
    // ---- P4: 0 reads; stage both A halves of t+2 (A(d,*) read-done after P3); counted vmcnt
    if (t + 2 < GEMM_NT) { STAGE_A(d, 0, t + 2); STAGE_A(d, 1, t + 2); }
    if (t < GEMM_NT - 2) { asm volatile("s_waitcnt vmcnt(6)" ::: "memory"); }
    else                 { asm volatile("s_waitcnt vmcnt(0)" ::: "memory"); }
    __builtin_amdgcn_sched_barrier(0);
    BAR();
    __builtin_amdgcn_s_setprio(1);
    MF_Q(4, 2);   // af mi4-7 x bfr[2..3], all in regs — no lgkm wait needed
    __builtin_amdgcn_s_setprio(0);
    BAR();
  }
}

// ---------------- QKV GEMM: x_bf16 @ qkv_w^T + qkv_b -> q,k (B,H,S,D) / v^T (B,H,D,S) ----------------
__global__ __launch_bounds__(512, 2) void qkv_gemm(const unsigned short* __restrict__ A,
                                                   const unsigned short* __restrict__ Bw,
                                                   const float* __restrict__ bias,
                                                   unsigned short* __restrict__ q,
                                                   unsigned short* __restrict__ kx,
                                                   unsigned short* __restrict__ vt) {
  __shared__ unsigned short S_A[32768];   // 64KB
  __shared__ unsigned short S_B[32768];   // 64KB
  const int bid = blockIdx.x;
  const int swz = (bid & 7) * (gridDim.x >> 3) + (bid >> 3);   // bijective XCD swizzle
  const int row0 = (swz & 127) * 256;      // 128 m-tiles
  const int col0 = (swz >> 7) * 256;       // 12 n-panels
  const int tid = threadIdx.x;
  const int wave = tid >> 6, lane = tid & 63;
  const int wm = wave >> 2, wn = wave & 3;
  const int l15 = lane & 15, quad = lane >> 4;
  f32x4 acc[8][4];
#pragma unroll
  for (int i = 0; i < 8; ++i)
#pragma unroll
    for (int j = 0; j < 4; ++j) acc[i][j] = (f32x4){0.f, 0.f, 0.f, 0.f};
  gemm256_loop(A, Bw, S_A, S_B, row0, col0, acc);
  const int which = col0 >> 10;  // block-uniform: 0=q 1=k 2=v
  const float QS = 0.125f * LOG2E;   // fold 1/sqrt(D) and exp2 domain scale into q
#pragma unroll
  for (int mi = 0; mi < 8; ++mi) {
    const int m = row0 + wm * 128 + mi * 16 + quad * 4;   // C row = quad*4+r
    const int bb = m >> 8;
    const int s0 = m & 255;   // +r stays in-window (no wrap)
#pragma unroll
    for (int nj = 0; nj < 4; ++nj) {
      const int n = col0 + wn * 64 + nj * 16 + l15;       // C col = lane&15
      const int hn = (n >> 6) & 15;
      const int dd2 = n & 63;
      const float bv = bias[n];
      // non-temporal stores: keep the 192MB q/k/vt stream from evicting A out of the LLC
      if (which == 0) {
        size_t base = ((size_t)(bb * HH + hn) * SS + s0) * DD + dd2;
#pragma unroll
        for (int r = 0; r < 4; ++r)
          __builtin_nontemporal_store(f2bf((acc[mi][nj][r] + bv) * QS), &q[base + (size_t)r * DD]);
      } else if (which == 1) {
        size_t base = ((size_t)(bb * HH + hn) * SS + s0) * DD + dd2;
#pragma unroll
        for (int r = 0; r < 4; ++r)
          __builtin_nontemporal_store(f2bf(acc[mi][nj][r] + bv), &kx[base + (size_t)r * DD]);
      } else {
        size_t base = ((size_t)(bb * HH + hn) * DD + dd2) * SS + s0;  // transposed v
        unsigned long long pv =
            (unsigned long long)f2bf(acc[mi][nj][0] + bv) |
            ((unsigned long long)f2bf(acc[mi][nj][1] + bv) << 16) |
            ((unsigned long long)f2bf(acc[mi][nj][2] + bv) << 32) |
            ((unsigned long long)f2bf(acc[mi][nj][3] + bv) << 48);
        __builtin_nontemporal_store(pv, (unsigned long long*)(vt + base));  // s0 % 4 == 0 -> 8B aligned
      }
    }
  }
}

// ---------------- attention: one block per (b,h), 4 q-blocks looped ----------------
__global__ __launch_bounds__(256) void attn_kernel(const unsigned short* __restrict__ q,
                                                   const unsigned short* __restrict__ kx,
                                                   const unsigned short* __restrict__ vt,
                                                   const float* __restrict__ biasC,
                                                   unsigned short* __restrict__ ctx) {
  __shared__ unsigned short Ks[256 * 64];   // 32KB, swizzled: chunk c at c^(row&7)
  __shared__ unsigned short P[4][16 * 256]; // 32KB, per-wave slices, swizzled
  const int tid = threadIdx.x;
  const int wave = tid >> 6, lane = tid & 63;
  const int l15 = lane & 15, quad = lane >> 4;
  const int swl = l15 & 7;
  const int bh = blockIdx.x;
  const int h = bh & 15;
  const int b_ = bh >> 4;
  const unsigned short* qp = q + (size_t)bh * SS * DD;
  const unsigned short* kp = kx + (size_t)bh * SS * DD;
  const unsigned short* vp = vt + (size_t)bh * SS * DD;

#pragma unroll
  for (int rr = 0; rr < 8; ++rr) {
    int gc = rr * 256 + tid;
    int row = gc >> 3, sc = gc & 7;
    int c = sc ^ (row & 7);
    gld16(kp + row * 64 + c * 8, Ks + (rr * 256 + wave * 64) * 8);
  }
  __syncthreads();

  unsigned short* Pw = &P[wave][0];
  for (int qblk = 0; qblk < 4; ++qblk) {
    const int qr0 = qblk * 64 + wave * 16;
    bf16x8 aq0 = *(const bf16x8*)(qp + (qr0 + l15) * DD + quad * 8);
    bf16x8 aq1 = *(const bf16x8*)(qp + (qr0 + l15) * DD + 32 + quad * 8);

    f32x4 sacc[16];
#pragma unroll
    for (int j = 0; j < 16; ++j) sacc[j] = (f32x4){0.f, 0.f, 0.f, 0.f};
#pragma unroll
    for (int j = 0; j < 16; ++j) {
      const unsigned short* krow = Ks + (j * 16 + l15) * 64;
      bf16x8 b0 = *(const bf16x8*)(krow + (quad ^ swl) * 8);
      bf16x8 b1 = *(const bf16x8*)(krow + ((4 + quad) ^ swl) * 8);
      sacc[j] = __builtin_amdgcn_mfma_f32_16x16x32_bf16(aq0, b0, sacc[j], 0, 0, 0);
      sacc[j] = __builtin_amdgcn_mfma_f32_16x16x32_bf16(aq1, b1, sacc[j], 0, 0, 0);
    }
#pragma unroll
    for (int r = 0; r < 4; ++r) {
      const int prow = quad * 4 + r;
      const float* bC = biasC + ((size_t)((h * 256 + qr0 + prow) * 16 + l15)) * 16;
      float4 bv0 = ((const float4*)bC)[0];
      float4 bv1 = ((const float4*)bC)[1];
      float4 bv2 = ((const float4*)bC)[2];
      float4 bv3 = ((const float4*)bC)[3];
      float bj[16] = {bv0.x, bv0.y, bv0.z, bv0.w, bv1.x, bv1.y, bv1.z, bv1.w,
                      bv2.x, bv2.y, bv2.z, bv2.w, bv3.x, bv3.y, bv3.z, bv3.w};
      float s = 0.f;
#pragma unroll
      for (int j = 0; j < 16; ++j) {
        float e = fast_exp2(sacc[j][r] + bj[j]);
        sacc[j][r] = e;
        s += e;
      }
#pragma unroll
      for (int m = 8; m >= 1; m >>= 1) s += __shfl_xor(s, m, 16);
      float rs = fast_rcp(s);
      const int psw = prow & 7;
#pragma unroll
      for (int j = 0; j < 16; ++j) {
        union { float f; unsigned int u; } cv; cv.f = sacc[j][r] * rs;
        unsigned short pb = (unsigned short)((cv.u + 0x8000u) >> 16);  // cheap RN
        Pw[prow * 256 + (((2 * j + (l15 >> 3)) ^ psw) << 3) + swl] = pb;
      }
    }
    f32x4 cacc[4];
#pragma unroll
    for (int nt = 0; nt < 4; ++nt) cacc[nt] = (f32x4){0.f, 0.f, 0.f, 0.f};
#pragma unroll
    for (int kk = 0; kk < 8; ++kk) {
      bf16x8 a = *(const bf16x8*)(Pw + l15 * 256 + (((kk * 4 + quad) ^ swl) << 3));
#pragma unroll
      for (int nt = 0; nt < 4; ++nt) {
        bf16x8 b = *(const bf16x8*)(vp + (nt * 16 + l15) * SS + kk * 32 + quad * 8);
        cacc[nt] = __builtin_amdgcn_mfma_f32_16x16x32_bf16(a, b, cacc[nt], 0, 0, 0);
      }
    }
#pragma unroll
    for (int nt = 0; nt < 4; ++nt)
#pragma unroll
      for (int r = 0; r < 4; ++r)
        ctx[(size_t)(b_ * SS + qr0 + quad * 4 + r) * EE + h * DD + nt * 16 + l15] =
            f2bf(cacc[nt][r]);
  }
}

// ---------------- out projection: ctx_bf16 @ out_w^T + out_b -> fp32 ----------------
__global__ __launch_bounds__(512, 2) void out_gemm(const unsigned short* __restrict__ A,
                                                   const unsigned short* __restrict__ Bw,
                                                   const float* __restrict__ bias,
                                                   float* __restrict__ out) {
  __shared__ unsigned short S_A[32768];
  __shared__ unsigned short S_B[32768];
  const int bid = blockIdx.x;
  const int swz = (bid & 7) * (gridDim.x >> 3) + (bid >> 3);
  const int row0 = (swz & 127) * 256;
  const int col0 = (swz >> 7) * 256;     // 4 n-panels
  const int tid = threadIdx.x;
  const int wave = tid >> 6, lane = tid & 63;
  const int wm = wave >> 2, wn = wave & 3;
  const int l15 = lane & 15, quad = lane >> 4;
  f32x4 acc[8][4];
#pragma unroll
  for (int i = 0; i < 8; ++i)
#pragma unroll
    for (int j = 0; j < 4; ++j) acc[i][j] = (f32x4){0.f, 0.f, 0.f, 0.f};
  gemm256_loop(A, Bw, S_A, S_B, row0, col0, acc);
#pragma unroll
  for (int mi = 0; mi < 8; ++mi) {
    const int m0 = row0 + wm * 128 + mi * 16 + quad * 4;
#pragma unroll
    for (int nj = 0; nj < 4; ++nj) {
      const int n = col0 + wn * 64 + nj * 16 + l15;
      const float bv = bias[n];
#pragma unroll
      for (int r = 0; r < 4; ++r)
        __builtin_nontemporal_store(acc[mi][nj][r] + bv, &out[(size_t)(m0 + r) * EE + n]);
    }
  }
}

// ---------------- workspace layout (bytes) ----------------
#define WS_XCTX  ((size_t)0)
#define WS_QKVW  ((size_t)67108864)
#define WS_OUTW  ((size_t)73400320)
#define WS_BIAS  ((size_t)75497472)
#define WS_Q     ((size_t)79691776)
#define WS_K     ((size_t)146800640)
#define WS_VT    ((size_t)213909504)
// total required: 281,018,368 bytes

extern "C" void kernel_launch(void* const* d_in, const int* in_sizes, int n_in,
                              void* d_out, int out_size, void* d_ws, size_t ws_size,
                              hipStream_t stream) {
  (void)in_sizes; (void)n_in; (void)out_size; (void)ws_size;
  const float* x      = (const float*)d_in[0];
  const float* qkv_w  = (const float*)d_in[1];
  const float* qkv_b  = (const float*)d_in[2];
  const float* out_w  = (const float*)d_in[3];
  const float* out_b  = (const float*)d_in[4];
  const float* btab   = (const float*)d_in[5];
  const int*   ridx   = (const int*)d_in[6];
  float* out = (float*)d_out;
  char* ws = (char*)d_ws;

  unsigned short* xctx  = (unsigned short*)(ws + WS_XCTX);
  unsigned short* qkvwb = (unsigned short*)(ws + WS_QKVW);
  unsigned short* outwb = (unsigned short*)(ws + WS_OUTW);
  float*          biasC = (float*)(ws + WS_BIAS);
  unsigned short* q     = (unsigned short*)(ws + WS_Q);
  unsigned short* k     = (unsigned short*)(ws + WS_K);
  unsigned short* vt    = (unsigned short*)(ws + WS_VT);

  prep_kernel<<<8192, 256, 0, stream>>>((const float4*)x, (const float4*)qkv_w,
                                        (const float4*)out_w, btab, ridx,
                                        (ushort4*)xctx, (ushort4*)qkvwb,
                                        (ushort4*)outwb, biasC);
  qkv_gemm<<<dim3((MM / 256) * ((3 * EE) / 256)), 512, 0, stream>>>(xctx, qkvwb, qkv_b,
                                                                    q, k, vt);
  attn_kernel<<<BB * HH, 256, 0, stream>>>(q, k, vt, biasC, xctx);
  out_gemm<<<dim3((MM / 256) * (EE / 256)), 512, 0, stream>>>(xctx, outwb, out_b, out);
}

// Round 5
// 780.147 us; speedup vs baseline: 1.0544x; 1.0544x over previous
//
#include <hip/hip_runtime.h>
#include <stdint.h>

// Problem constants
#define BB 128
#define SS 256
#define EE 1024
#define HH 16
#define DD 64
#define MM (BB*SS)   // 32768

#define LOG2E 1.44269504088896f

typedef __attribute__((ext_vector_type(8))) short bf16x8;
typedef __attribute__((ext_vector_type(4))) float f32x4;

__device__ __forceinline__ unsigned short f2bf(float f) {
  union { float f; unsigned int u; } c; c.f = f;
  unsigned int u = c.u;
  u += 0x7fffu + ((u >> 16) & 1u);   // round-to-nearest-even
  return (unsigned short)(u >> 16);
}

__device__ __forceinline__ float fast_exp2(float x) {
#if __has_builtin(__builtin_amdgcn_exp2f)
  return __builtin_amdgcn_exp2f(x);
#else
  return exp2f(x);
#endif
}

__device__ __forceinline__ float fast_rcp(float x) {
#if __has_builtin(__builtin_amdgcn_rcpf)
  return __builtin_amdgcn_rcpf(x);
#else
  return 1.0f / x;
#endif
}

__device__ __forceinline__ void gld16(const unsigned short* g, unsigned short* l) {
  // async global->LDS, 16B/lane; LDS dest = wave-uniform base + lane*16
  __builtin_amdgcn_global_load_lds((__attribute__((address_space(1))) void*)(g),
                                   (__attribute__((address_space(3))) void*)(l), 16, 0, 0);
}

// ---------------- merged prep: casts + bias layout build ----------------
__global__ __launch_bounds__(256) void prep_kernel(const float4* __restrict__ x4,
                                                   const float4* __restrict__ qw,
                                                   const float4* __restrict__ ow,
                                                   const float* __restrict__ btab,
                                                   const int* __restrict__ ridx,
                                                   ushort4* __restrict__ xb,
                                                   ushort4* __restrict__ qwb,
                                                   ushort4* __restrict__ owb,
                                                   float* __restrict__ biasC) {
  const int NX = (MM * EE) / 4;       // 8388608 float4
  const int NQ = (3 * EE * EE) / 4;   // 786432 float4
  const int NO = (EE * EE) / 4;       // 262144 float4
  const int NBIAS = HH * SS * SS;     // 1048576 floats
  const int total = NX + NQ + NO + NBIAS;   // 10485760
  int stride = gridDim.x * blockDim.x;
  for (int i = blockIdx.x * blockDim.x + threadIdx.x; i < total; i += stride) {
    if (i < NX) {
      float4 v = x4[i];
      ushort4 r; r.x = f2bf(v.x); r.y = f2bf(v.y); r.z = f2bf(v.z); r.w = f2bf(v.w);
      xb[i] = r;
    } else if (i < NX + NQ) {
      int t = i - NX;
      float4 v = qw[t];
      ushort4 r; r.x = f2bf(v.x); r.y = f2bf(v.y); r.z = f2bf(v.z); r.w = f2bf(v.w);
      qwb[t] = r;
    } else if (i < NX + NQ + NO) {
      int t = i - (NX + NQ);
      float4 v = ow[t];
      ushort4 r; r.x = f2bf(v.x); r.y = f2bf(v.y); r.z = f2bf(v.z); r.w = f2bf(v.w);
      owb[t] = r;
    } else {
      int t = i - (NX + NQ + NO);
      int h   = t >> 16;          // [H][row][lo][hi]
      int row = (t >> 8) & 255;
      int lo  = (t >> 4) & 15;
      int hi  = t & 15;
      int col = hi * 16 + lo;
      biasC[t] = btab[ridx[row * SS + col] * HH + h] * LOG2E;
    }
  }
}

// ---------------- 256x256 8-phase GEMM mainloop (K = 1024, BK = 64) ----------------
// 512 threads = 8 waves (2 M x 4 N), per-wave C = 128x64 = 8x4 fragments.
// LDS: per matrix 2 dbuf x 2 k-half units of [256 rows][32 bf16] = 64KB; 128KB total.
// Staging unit = one k-half (16KB, 2 x global_load_lds_dwordx4 per wave), LDS-linear;
// the chunk^( (row>>1)&3 ) bank swizzle is applied by pre-swizzling the GLOBAL source.
// Compiler-scheduled variant (R1, best measured): waits are compiler-inserted; the
// hand-counted vmcnt/asm-ds_read variant (R4) measured WORSE — do not reintroduce.
#define GEMM_NT 16

__device__ __forceinline__ void mfma16(f32x4& c, bf16x8 a, bf16x8 b) {
  c = __builtin_amdgcn_mfma_f32_16x16x32_bf16(a, b, c, 0, 0, 0);
}

#define STAGE_A(buf, kh, tt) do { \
    unsigned short* _d = S_A + ((buf)*2 + (kh))*8192; \
    gld16(srcA0 + (tt)*64 + (kh)*32, _d + ldso0); \
    gld16(srcA1 + (tt)*64 + (kh)*32, _d + ldso1); } while (0)
#define STAGE_B(buf, kh, tt) do { \
    unsigned short* _d = S_B + ((buf)*2 + (kh))*8192; \
    gld16(srcB0 + (tt)*64 + (kh)*32, _d + ldso0); \
    gld16(srcB1 + (tt)*64 + (kh)*32, _d + ldso1); } while (0)
#define LOAD_A8(buf, kh) do { \
    const unsigned short* _u = S_A + ((buf)*2 + (kh))*8192 + aoff; \
    _Pragma("unroll") for (int mi = 0; mi < 8; ++mi) \
      af[mi] = *(const bf16x8*)(_u + mi*512); } while (0)
#define LOAD_B2(buf, kh, nj0) do { \
    const unsigned short* _u = S_B + ((buf)*2 + (kh))*8192 + boff; \
    bfr[(nj0)]   = *(const bf16x8*)(_u + (nj0)*512); \
    bfr[(nj0)+1] = *(const bf16x8*)(_u + ((nj0)+1)*512); } while (0)
#define MFMA_Q(nj0) do { \
    _Pragma("unroll") for (int mi = 0; mi < 8; ++mi) { \
      mfma16(acc[mi][(nj0)],   af[mi], bfr[(nj0)]); \
      mfma16(acc[mi][(nj0)+1], af[mi], bfr[(nj0)+1]); } } while (0)
#define WAIT_LGKM0() do { asm volatile("s_waitcnt lgkmcnt(0)" ::: "memory"); \
                          __builtin_amdgcn_sched_barrier(0); } while (0)

__device__ __forceinline__ void gemm256_loop(const unsigned short* __restrict__ A,
                                             const unsigned short* __restrict__ Bw,
                                             unsigned short* S_A, unsigned short* S_B,
                                             int row0, int col0, f32x4 (&acc)[8][4]) {
  const int tid = threadIdx.x;
  const int wave = tid >> 6, lane = tid & 63;
  const int wm = wave >> 2, wn = wave & 3;
  const int l15 = lane & 15, quad = lane >> 4;
  // fragment read offsets (elements) within an 8192-element [256][32] unit
  const int cq = quad ^ ((l15 >> 1) & 3);                 // bank swizzle key (row bits 1-2)
  const int aoff = (wm * 128 + l15) * 32 + cq * 8;
  const int boff = (wn * 64 + l15) * 32 + cq * 8;
  // staging: lane li = g*512+tid covers row li>>2, LDS chunk li&3; global chunk swizzled
  const int r0g = tid >> 2, c0g = tid & 3;
  const int gc = c0g ^ ((r0g >> 1) & 3);                  // same key for g=0/1 (row+128)
  const unsigned short* srcA0 = A  + (size_t)(row0 + r0g) * EE + gc * 8;
  const unsigned short* srcA1 = A  + (size_t)(row0 + 128 + r0g) * EE + gc * 8;
  const unsigned short* srcB0 = Bw + (size_t)(col0 + r0g) * EE + gc * 8;
  const unsigned short* srcB1 = Bw + (size_t)(col0 + 128 + r0g) * EE + gc * 8;
  const int ldso0 = wave * 512;          // wave-uniform LDS element offsets
  const int ldso1 = 4096 + wave * 512;

  // prologue: tile0 (A0,B0,A1,B1) + tile1 (A0,B0,A1) = 14 loads; vmcnt(6) -> tile0 landed
  STAGE_A(0, 0, 0); STAGE_B(0, 0, 0); STAGE_A(0, 1, 0); STAGE_B(0, 1, 0);
  STAGE_A(1, 0, 1); STAGE_B(1, 0, 1); STAGE_A(1, 1, 1);
  asm volatile("s_waitcnt vmcnt(6)" ::: "memory");
  __builtin_amdgcn_sched_barrier(0);
  __builtin_amdgcn_s_barrier();

  bf16x8 af[8], bfr[4];
  for (int t = 0; t < GEMM_NT; ++t) {
    const int d = t & 1;
    // ---- P1: kh0 x nj{0,1}; stage B-k1(t+1) into buf d^1 (read-done in prev group P3/P4)
    LOAD_A8(d, 0); LOAD_B2(d, 0, 0);
    if (t + 1 < GEMM_NT) STAGE_B(d ^ 1, 1, t + 1);
    __builtin_amdgcn_s_barrier();
    WAIT_LGKM0();
    __builtin_amdgcn_s_setprio(1);
    MFMA_Q(0);
    __builtin_amdgcn_s_setprio(0);
    __builtin_amdgcn_s_barrier();
    // ---- P2: kh0 x nj{2,3}; stage A-k0(t+2) over tile t A-k0 (fully read in P1)
    LOAD_B2(d, 0, 2);
    if (t + 2 < GEMM_NT) STAGE_A(d, 0, t + 2);
    __builtin_amdgcn_s_barrier();
    WAIT_LGKM0();
    __builtin_amdgcn_s_setprio(1);
    MFMA_Q(2);
    __builtin_amdgcn_s_setprio(0);
    __builtin_amdgcn_s_barrier();
    // ---- P3: kh1 x nj{0,1}; stage B-k0(t+2) over tile t B-k0 (fully read in P1+P2)
    LOAD_A8(d, 1); LOAD_B2(d, 1, 0);
    if (t + 2 < GEMM_NT) STAGE_B(d, 0, t + 2);
    __builtin_amdgcn_s_barrier();
    WAIT_LGKM0();
    __builtin_amdgcn_s_setprio(1);
    MFMA_Q(0);
    __builtin_amdgcn_s_setprio(0);
    __builtin_amdgcn_s_barrier();
    // ---- P4: kh1 x nj{2,3}; stage A-k1(t+2) over tile t A-k1 (fully read in P3)
    LOAD_B2(d, 1, 2);
    if (t + 2 < GEMM_NT) STAGE_A(d, 1, t + 2);
    if (t < GEMM_NT - 2) { asm volatile("s_waitcnt vmcnt(6)" ::: "memory"); }
    else                 { asm volatile("s_waitcnt vmcnt(0)" ::: "memory"); }
    __builtin_amdgcn_sched_barrier(0);
    __builtin_amdgcn_s_barrier();
    WAIT_LGKM0();
    __builtin_amdgcn_s_setprio(1);
    MFMA_Q(2);
    __builtin_amdgcn_s_setprio(0);
    __builtin_amdgcn_s_barrier();
  }
}

// ---------------- QKV GEMM: x_bf16 @ qkv_w^T + qkv_b -> q,k (B,H,S,D) / v^T (B,H,D,S) ----------------
__global__ __launch_bounds__(512, 2) void qkv_gemm(const unsigned short* __restrict__ A,
                                                   const unsigned short* __restrict__ Bw,
                                                   const float* __restrict__ bias,
                                                   unsigned short* __restrict__ q,
                                                   unsigned short* __restrict__ kx,
                                                   unsigned short* __restrict__ vt) {
  __shared__ unsigned short S_A[32768];   // 64KB
  __shared__ unsigned short S_B[32768];   // 64KB
  // XCD-private row-band mapping: XCD x owns row-tiles [16x, 16x+16) (8MB A band,
  // LLC-resident after the first panel sweep); panels swept band-locally so A is
  // HBM-fetched once instead of once per n-panel (R4 FETCH_SIZE: 405MB, ideal 70MB).
  const int bid = blockIdx.x;
  const int xcd = bid & 7, j = bid >> 3;          // 192 blocks per XCD
  const int row0 = (xcd * 16 + (j & 15)) * 256;   // band-local row tile
  const int col0 = (j >> 4) * 256;                // 12 col panels
  const int tid = threadIdx.x;
  const int wave = tid >> 6, lane = tid & 63;
  const int wm = wave >> 2, wn = wave & 3;
  const int l15 = lane & 15, quad = lane >> 4;
  f32x4 acc[8][4];
#pragma unroll
  for (int i = 0; i < 8; ++i)
#pragma unroll
    for (int j2 = 0; j2 < 4; ++j2) acc[i][j2] = (f32x4){0.f, 0.f, 0.f, 0.f};
  gemm256_loop(A, Bw, S_A, S_B, row0, col0, acc);
  const int which = col0 >> 10;  // block-uniform: 0=q 1=k 2=v
  const float QS = 0.125f * LOG2E;   // fold 1/sqrt(D) and the exp2 domain scale into q
#pragma unroll
  for (int mi = 0; mi < 8; ++mi) {
    const int m = row0 + wm * 128 + mi * 16 + quad * 4;   // C row = quad*4+r
    const int bb = m >> 8;
    const int s0 = m & 255;   // +r stays in-window (no wrap)
#pragma unroll
    for (int nj = 0; nj < 4; ++nj) {
      const int n = col0 + wn * 64 + nj * 16 + l15;       // C col = lane&15
      const int hn = (n >> 6) & 15;
      const int dd2 = n & 63;
      const float bv = bias[n];
      if (which == 0) {
        size_t base = ((size_t)(bb * HH + hn) * SS + s0) * DD + dd2;
#pragma unroll
        for (int r = 0; r < 4; ++r)
          q[base + (size_t)r * DD] = f2bf((acc[mi][nj][r] + bv) * QS);
      } else if (which == 1) {
        size_t base = ((size_t)(bb * HH + hn) * SS + s0) * DD + dd2;
#pragma unroll
        for (int r = 0; r < 4; ++r)
          kx[base + (size_t)r * DD] = f2bf(acc[mi][nj][r] + bv);
      } else {
        size_t base = ((size_t)(bb * HH + hn) * DD + dd2) * SS + s0;  // transposed v
        ushort4 pk;
        pk.x = f2bf(acc[mi][nj][0] + bv);
        pk.y = f2bf(acc[mi][nj][1] + bv);
        pk.z = f2bf(acc[mi][nj][2] + bv);
        pk.w = f2bf(acc[mi][nj][3] + bv);
        *(ushort4*)(vt + base) = pk;
      }
    }
  }
}

// ---------------- attention: one block per (b,h), 4 q-blocks looped ----------------
__global__ __launch_bounds__(256) void attn_kernel(const unsigned short* __restrict__ q,
                                                   const unsigned short* __restrict__ kx,
                                                   const unsigned short* __restrict__ vt,
                                                   const float* __restrict__ biasC,
                                                   unsigned short* __restrict__ ctx) {
  __shared__ unsigned short Ks[256 * 64];   // 32KB, swizzled: chunk c at c^(row&7)
  __shared__ unsigned short P[4][16 * 256]; // 32KB, per-wave slices, swizzled
  const int tid = threadIdx.x;
  const int wave = tid >> 6, lane = tid & 63;
  const int l15 = lane & 15, quad = lane >> 4;
  const int swl = l15 & 7;
  const int bh = blockIdx.x;
  const int h = bh & 15;
  const int b_ = bh >> 4;
  const unsigned short* qp = q + (size_t)bh * SS * DD;
  const unsigned short* kp = kx + (size_t)bh * SS * DD;
  const unsigned short* vp = vt + (size_t)bh * SS * DD;

#pragma unroll
  for (int rr = 0; rr < 8; ++rr) {
    int gc = rr * 256 + tid;
    int row = gc >> 3, sc = gc & 7;
    int c = sc ^ (row & 7);
    gld16(kp + row * 64 + c * 8, Ks + (rr * 256 + wave * 64) * 8);
  }
  __syncthreads();

  unsigned short* Pw = &P[wave][0];
  for (int qblk = 0; qblk < 4; ++qblk) {
    const int qr0 = qblk * 64 + wave * 16;
    bf16x8 aq0 = *(const bf16x8*)(qp + (qr0 + l15) * DD + quad * 8);
    bf16x8 aq1 = *(const bf16x8*)(qp + (qr0 + l15) * DD + 32 + quad * 8);

    f32x4 sacc[16];
#pragma unroll
    for (int j = 0; j < 16; ++j) sacc[j] = (f32x4){0.f, 0.f, 0.f, 0.f};
#pragma unroll
    for (int j = 0; j < 16; ++j) {
      const unsigned short* krow = Ks + (j * 16 + l15) * 64;
      bf16x8 b0 = *(const bf16x8*)(krow + (quad ^ swl) * 8);
      bf16x8 b1 = *(const bf16x8*)(krow + ((4 + quad) ^ swl) * 8);
      sacc[j] = __builtin_amdgcn_mfma_f32_16x16x32_bf16(aq0, b0, sacc[j], 0, 0, 0);
      sacc[j] = __builtin_amdgcn_mfma_f32_16x16x32_bf16(aq1, b1, sacc[j], 0, 0, 0);
    }
#pragma unroll
    for (int r = 0; r < 4; ++r) {
      const int prow = quad * 4 + r;
      const float* bC = biasC + ((size_t)((h * 256 + qr0 + prow) * 16 + l15)) * 16;
      float4 bv0 = ((const float4*)bC)[0];
      float4 bv1 = ((const float4*)bC)[1];
      float4 bv2 = ((const float4*)bC)[2];
      float4 bv3 = ((const float4*)bC)[3];
      float bj[16] = {bv0.x, bv0.y, bv0.z, bv0.w, bv1.x, bv1.y, bv1.z, bv1.w,
                      bv2.x, bv2.y, bv2.z, bv2.w, bv3.x, bv3.y, bv3.z, bv3.w};
      float s = 0.f;
#pragma unroll
      for (int j = 0; j < 16; ++j) {
        float e = fast_exp2(sacc[j][r] + bj[j]);
        sacc[j][r] = e;
        s += e;
      }
#pragma unroll
      for (int m = 8; m >= 1; m >>= 1) s += __shfl_xor(s, m, 16);
      float rs = fast_rcp(s);
      const int psw = prow & 7;
#pragma unroll
      for (int j = 0; j < 16; ++j) {
        union { float f; unsigned int u; } cv; cv.f = sacc[j][r] * rs;
        unsigned short pb = (unsigned short)((cv.u + 0x8000u) >> 16);  // cheap RN
        Pw[prow * 256 + (((2 * j + (l15 >> 3)) ^ psw) << 3) + swl] = pb;
      }
    }
    f32x4 cacc[4];
#pragma unroll
    for (int nt = 0; nt < 4; ++nt) cacc[nt] = (f32x4){0.f, 0.f, 0.f, 0.f};
#pragma unroll
    for (int kk = 0; kk < 8; ++kk) {
      bf16x8 a = *(const bf16x8*)(Pw + l15 * 256 + (((kk * 4 + quad) ^ swl) << 3));
#pragma unroll
      for (int nt = 0; nt < 4; ++nt) {
        bf16x8 b = *(const bf16x8*)(vp + (nt * 16 + l15) * SS + kk * 32 + quad * 8);
        cacc[nt] = __builtin_amdgcn_mfma_f32_16x16x32_bf16(a, b, cacc[nt], 0, 0, 0);
      }
    }
#pragma unroll
    for (int nt = 0; nt < 4; ++nt)
#pragma unroll
      for (int r = 0; r < 4; ++r)
        ctx[(size_t)(b_ * SS + qr0 + quad * 4 + r) * EE + h * DD + nt * 16 + l15] =
            f2bf(cacc[nt][r]);
  }
}

// ---------------- out projection: ctx_bf16 @ out_w^T + out_b -> fp32 ----------------
__global__ __launch_bounds__(512, 2) void out_gemm(const unsigned short* __restrict__ A,
                                                   const unsigned short* __restrict__ Bw,
                                                   const float* __restrict__ bias,
                                                   float* __restrict__ out) {
  __shared__ unsigned short S_A[32768];
  __shared__ unsigned short S_B[32768];
  const int bid = blockIdx.x;
  const int xcd = bid & 7, j = bid >> 3;          // 64 blocks per XCD
  const int row0 = (xcd * 16 + (j & 15)) * 256;   // XCD-private row band
  const int col0 = (j >> 4) * 256;                // 4 col panels
  const int tid = threadIdx.x;
  const int wave = tid >> 6, lane = tid & 63;
  const int wm = wave >> 2, wn = wave & 3;
  const int l15 = lane & 15, quad = lane >> 4;
  f32x4 acc[8][4];
#pragma unroll
  for (int i = 0; i < 8; ++i)
#pragma unroll
    for (int j2 = 0; j2 < 4; ++j2) acc[i][j2] = (f32x4){0.f, 0.f, 0.f, 0.f};
  gemm256_loop(A, Bw, S_A, S_B, row0, col0, acc);
#pragma unroll
  for (int mi = 0; mi < 8; ++mi) {
    const int m0 = row0 + wm * 128 + mi * 16 + quad * 4;
#pragma unroll
    for (int nj = 0; nj < 4; ++nj) {
      const int n = col0 + wn * 64 + nj * 16 + l15;
      const float bv = bias[n];
#pragma unroll
      for (int r = 0; r < 4; ++r)
        out[(size_t)(m0 + r) * EE + n] = acc[mi][nj][r] + bv;
    }
  }
}

// ---------------- workspace layout (bytes) ----------------
#define WS_XCTX  ((size_t)0)
#define WS_QKVW  ((size_t)67108864)
#define WS_OUTW  ((size_t)73400320)
#define WS_BIAS  ((size_t)75497472)
#define WS_Q     ((size_t)79691776)
#define WS_K     ((size_t)146800640)
#define WS_VT    ((size_t)213909504)
// total required: 281,018,368 bytes

extern "C" void kernel_launch(void* const* d_in, const int* in_sizes, int n_in,
                              void* d_out, int out_size, void* d_ws, size_t ws_size,
                              hipStream_t stream) {
  (void)in_sizes; (void)n_in; (void)out_size; (void)ws_size;
  const float* x      = (const float*)d_in[0];
  const float* qkv_w  = (const float*)d_in[1];
  const float* qkv_b  = (const float*)d_in[2];
  const float* out_w  = (const float*)d_in[3];
  const float* out_b  = (const float*)d_in[4];
  const float* btab   = (const float*)d_in[5];
  const int*   ridx   = (const int*)d_in[6];
  float* out = (float*)d_out;
  char* ws = (char*)d_ws;

  unsigned short* xctx  = (unsigned short*)(ws + WS_XCTX);
  unsigned short* qkvwb = (unsigned short*)(ws + WS_QKVW);
  unsigned short* outwb = (unsigned short*)(ws + WS_OUTW);
  float*          biasC = (float*)(ws + WS_BIAS);
  unsigned short* q     = (unsigned short*)(ws + WS_Q);
  unsigned short* k     = (unsigned short*)(ws + WS_K);
  unsigned short* vt    = (unsigned short*)(ws + WS_VT);

  prep_kernel<<<8192, 256, 0, stream>>>((const float4*)x, (const float4*)qkv_w,
                                        (const float4*)out_w, btab, ridx,
                                        (ushort4*)xctx, (ushort4*)qkvwb,
                                        (ushort4*)outwb, biasC);
  qkv_gemm<<<dim3((MM / 256) * ((3 * EE) / 256)), 512, 0, stream>>>(xctx, qkvwb, qkv_b,
                                                                    q, k, vt);
  attn_kernel<<<BB * HH, 256, 0, stream>>>(q, k, vt, biasC, xctx);
  out_gemm<<<dim3((MM / 256) * (EE / 256)), 512, 0, stream>>>(xctx, outwb, out_b, out);
}

// Round 6
// 759.361 us; speedup vs baseline: 1.0833x; 1.0274x over previous
//
#include <hip/hip_runtime.h>
#include <stdint.h>

// Problem constants
#define BB 128
#define SS 256
#define EE 1024
#define HH 16
#define DD 64
#define MM (BB*SS)   // 32768

#define LOG2E 1.44269504088896f

typedef __attribute__((ext_vector_type(8))) short bf16x8;
typedef __attribute__((ext_vector_type(4))) float f32x4;

__device__ __forceinline__ unsigned short f2bf(float f) {
  union { float f; unsigned int u; } c; c.f = f;
  unsigned int u = c.u;
  u += 0x7fffu + ((u >> 16) & 1u);   // round-to-nearest-even
  return (unsigned short)(u >> 16);
}

__device__ __forceinline__ float fast_exp2(float x) {
#if __has_builtin(__builtin_amdgcn_exp2f)
  return __builtin_amdgcn_exp2f(x);
#else
  return exp2f(x);
#endif
}

__device__ __forceinline__ float fast_rcp(float x) {
#if __has_builtin(__builtin_amdgcn_rcpf)
  return __builtin_amdgcn_rcpf(x);
#else
  return 1.0f / x;
#endif
}

__device__ __forceinline__ void gld16(const unsigned short* g, unsigned short* l) {
  // async global->LDS, 16B/lane; LDS dest = wave-uniform base + lane*16
  __builtin_amdgcn_global_load_lds((__attribute__((address_space(1))) void*)(g),
                                   (__attribute__((address_space(3))) void*)(l), 16, 0, 0);
}

// ---------------- merged prep: casts + bias layout build ----------------
__global__ __launch_bounds__(256) void prep_kernel(const float4* __restrict__ x4,
                                                   const float4* __restrict__ qw,
                                                   const float4* __restrict__ ow,
                                                   const float* __restrict__ btab,
                                                   const int* __restrict__ ridx,
                                                   ushort4* __restrict__ xb,
                                                   ushort4* __restrict__ qwb,
                                                   ushort4* __restrict__ owb,
                                                   float* __restrict__ biasC) {
  const int NX = (MM * EE) / 4;       // 8388608 float4
  const int NQ = (3 * EE * EE) / 4;   // 786432 float4
  const int NO = (EE * EE) / 4;       // 262144 float4
  const int NBIAS = HH * SS * SS;     // 1048576 floats
  const int total = NX + NQ + NO + NBIAS;   // 10485760
  int stride = gridDim.x * blockDim.x;
  for (int i = blockIdx.x * blockDim.x + threadIdx.x; i < total; i += stride) {
    if (i < NX) {
      float4 v = x4[i];
      ushort4 r; r.x = f2bf(v.x); r.y = f2bf(v.y); r.z = f2bf(v.z); r.w = f2bf(v.w);
      xb[i] = r;
    } else if (i < NX + NQ) {
      int t = i - NX;
      float4 v = qw[t];
      ushort4 r; r.x = f2bf(v.x); r.y = f2bf(v.y); r.z = f2bf(v.z); r.w = f2bf(v.w);
      qwb[t] = r;
    } else if (i < NX + NQ + NO) {
      int t = i - (NX + NQ);
      float4 v = ow[t];
      ushort4 r; r.x = f2bf(v.x); r.y = f2bf(v.y); r.z = f2bf(v.z); r.w = f2bf(v.w);
      owb[t] = r;
    } else {
      int t = i - (NX + NQ + NO);
      int h   = t >> 16;          // [H][row][lo][hi]
      int row = (t >> 8) & 255;
      int lo  = (t >> 4) & 15;
      int hi  = t & 15;
      int col = hi * 16 + lo;
      biasC[t] = btab[ridx[row * SS + col] * HH + h] * LOG2E;
    }
  }
}

// ---------------- 256x256 8-phase GEMM mainloop (K = 1024, BK = 64) ----------------
// Compiler-scheduled variant (R1, best measured 280us). R4 manual-asm variant was
// WORSE; R5 band mapping halved FETCH (405->221MB) at unchanged time — kept.
#define GEMM_NT 16

__device__ __forceinline__ void mfma16(f32x4& c, bf16x8 a, bf16x8 b) {
  c = __builtin_amdgcn_mfma_f32_16x16x32_bf16(a, b, c, 0, 0, 0);
}

#define STAGE_A(buf, kh, tt) do { \
    unsigned short* _d = S_A + ((buf)*2 + (kh))*8192; \
    gld16(srcA0 + (tt)*64 + (kh)*32, _d + ldso0); \
    gld16(srcA1 + (tt)*64 + (kh)*32, _d + ldso1); } while (0)
#define STAGE_B(buf, kh, tt) do { \
    unsigned short* _d = S_B + ((buf)*2 + (kh))*8192; \
    gld16(srcB0 + (tt)*64 + (kh)*32, _d + ldso0); \
    gld16(srcB1 + (tt)*64 + (kh)*32, _d + ldso1); } while (0)
#define LOAD_A8(buf, kh) do { \
    const unsigned short* _u = S_A + ((buf)*2 + (kh))*8192 + aoff; \
    _Pragma("unroll") for (int mi = 0; mi < 8; ++mi) \
      af[mi] = *(const bf16x8*)(_u + mi*512); } while (0)
#define LOAD_B2(buf, kh, nj0) do { \
    const unsigned short* _u = S_B + ((buf)*2 + (kh))*8192 + boff; \
    bfr[(nj0)]   = *(const bf16x8*)(_u + (nj0)*512); \
    bfr[(nj0)+1] = *(const bf16x8*)(_u + ((nj0)+1)*512); } while (0)
#define MFMA_Q(nj0) do { \
    _Pragma("unroll") for (int mi = 0; mi < 8; ++mi) { \
      mfma16(acc[mi][(nj0)],   af[mi], bfr[(nj0)]); \
      mfma16(acc[mi][(nj0)+1], af[mi], bfr[(nj0)+1]); } } while (0)
#define WAIT_LGKM0() do { asm volatile("s_waitcnt lgkmcnt(0)" ::: "memory"); \
                          __builtin_amdgcn_sched_barrier(0); } while (0)

__device__ __forceinline__ void gemm256_loop(const unsigned short* __restrict__ A,
                                             const unsigned short* __restrict__ Bw,
                                             unsigned short* S_A, unsigned short* S_B,
                                             int row0, int col0, f32x4 (&acc)[8][4]) {
  const int tid = threadIdx.x;
  const int wave = tid >> 6, lane = tid & 63;
  const int wm = wave >> 2, wn = wave & 3;
  const int l15 = lane & 15, quad = lane >> 4;
  const int cq = quad ^ ((l15 >> 1) & 3);                 // bank swizzle key (row bits 1-2)
  const int aoff = (wm * 128 + l15) * 32 + cq * 8;
  const int boff = (wn * 64 + l15) * 32 + cq * 8;
  const int r0g = tid >> 2, c0g = tid & 3;
  const int gc = c0g ^ ((r0g >> 1) & 3);                  // same key for g=0/1 (row+128)
  const unsigned short* srcA0 = A  + (size_t)(row0 + r0g) * EE + gc * 8;
  const unsigned short* srcA1 = A  + (size_t)(row0 + 128 + r0g) * EE + gc * 8;
  const unsigned short* srcB0 = Bw + (size_t)(col0 + r0g) * EE + gc * 8;
  const unsigned short* srcB1 = Bw + (size_t)(col0 + 128 + r0g) * EE + gc * 8;
  const int ldso0 = wave * 512;          // wave-uniform LDS element offsets
  const int ldso1 = 4096 + wave * 512;

  // prologue: tile0 (A0,B0,A1,B1) + tile1 (A0,B0,A1) = 14 loads; vmcnt(6) -> tile0 landed
  STAGE_A(0, 0, 0); STAGE_B(0, 0, 0); STAGE_A(0, 1, 0); STAGE_B(0, 1, 0);
  STAGE_A(1, 0, 1); STAGE_B(1, 0, 1); STAGE_A(1, 1, 1);
  asm volatile("s_waitcnt vmcnt(6)" ::: "memory");
  __builtin_amdgcn_sched_barrier(0);
  __builtin_amdgcn_s_barrier();

  bf16x8 af[8], bfr[4];
  for (int t = 0; t < GEMM_NT; ++t) {
    const int d = t & 1;
    // ---- P1: kh0 x nj{0,1}; stage B-k1(t+1) into buf d^1
    LOAD_A8(d, 0); LOAD_B2(d, 0, 0);
    if (t + 1 < GEMM_NT) STAGE_B(d ^ 1, 1, t + 1);
    __builtin_amdgcn_s_barrier();
    WAIT_LGKM0();
    __builtin_amdgcn_s_setprio(1);
    MFMA_Q(0);
    __builtin_amdgcn_s_setprio(0);
    __builtin_amdgcn_s_barrier();
    // ---- P2: kh0 x nj{2,3}; stage A-k0(t+2)
    LOAD_B2(d, 0, 2);
    if (t + 2 < GEMM_NT) STAGE_A(d, 0, t + 2);
    __builtin_amdgcn_s_barrier();
    WAIT_LGKM0();
    __builtin_amdgcn_s_setprio(1);
    MFMA_Q(2);
    __builtin_amdgcn_s_setprio(0);
    __builtin_amdgcn_s_barrier();
    // ---- P3: kh1 x nj{0,1}; stage B-k0(t+2)
    LOAD_A8(d, 1); LOAD_B2(d, 1, 0);
    if (t + 2 < GEMM_NT) STAGE_B(d, 0, t + 2);
    __builtin_amdgcn_s_barrier();
    WAIT_LGKM0();
    __builtin_amdgcn_s_setprio(1);
    MFMA_Q(0);
    __builtin_amdgcn_s_setprio(0);
    __builtin_amdgcn_s_barrier();
    // ---- P4: kh1 x nj{2,3}; stage A-k1(t+2); counted vmcnt
    LOAD_B2(d, 1, 2);
    if (t + 2 < GEMM_NT) STAGE_A(d, 1, t + 2);
    if (t < GEMM_NT - 2) { asm volatile("s_waitcnt vmcnt(6)" ::: "memory"); }
    else                 { asm volatile("s_waitcnt vmcnt(0)" ::: "memory"); }
    __builtin_amdgcn_sched_barrier(0);
    __builtin_amdgcn_s_barrier();
    WAIT_LGKM0();
    __builtin_amdgcn_s_setprio(1);
    MFMA_Q(2);
    __builtin_amdgcn_s_setprio(0);
    __builtin_amdgcn_s_barrier();
  }
}

// ---------------- QKV GEMM: x_bf16 @ qkv_w^T + qkv_b -> q,k (B,H,S,D) / v^T (frag layout) ----------------
// vt fragment-native layout (R6): element V[s][d] of head (b,h) stored at
//   bh*16384 + ((s>>5)*4 + (d>>4))*512 + (((s>>3)&3)*16 + (d&15))*8 + (s&7)
// so attn's PV B-fragment load per (kk,nt) is vp + (kk*4+nt)*512 + lane*8 —
// one dense, lane-linear 1KB load (was 64-line scatter at 512B stride).
__global__ __launch_bounds__(512, 2) void qkv_gemm(const unsigned short* __restrict__ A,
                                                   const unsigned short* __restrict__ Bw,
                                                   const float* __restrict__ bias,
                                                   unsigned short* __restrict__ q,
                                                   unsigned short* __restrict__ kx,
                                                   unsigned short* __restrict__ vt) {
  __shared__ unsigned short S_A[32768];   // 64KB
  __shared__ unsigned short S_B[32768];   // 64KB
  // XCD-private row-band mapping (R5): XCD x owns row-tiles [16x,16x+16); panels
  // swept band-locally (FETCH 405->221MB).
  const int bid = blockIdx.x;
  const int xcd = bid & 7, j = bid >> 3;          // 192 blocks per XCD
  const int row0 = (xcd * 16 + (j & 15)) * 256;   // band-local row tile
  const int col0 = (j >> 4) * 256;                // 12 col panels
  const int tid = threadIdx.x;
  const int wave = tid >> 6, lane = tid & 63;
  const int wm = wave >> 2, wn = wave & 3;
  const int l15 = lane & 15, quad = lane >> 4;
  f32x4 acc[8][4];
#pragma unroll
  for (int i = 0; i < 8; ++i)
#pragma unroll
    for (int j2 = 0; j2 < 4; ++j2) acc[i][j2] = (f32x4){0.f, 0.f, 0.f, 0.f};
  gemm256_loop(A, Bw, S_A, S_B, row0, col0, acc);
  const int which = col0 >> 10;  // block-uniform: 0=q 1=k 2=v
  const float QS = 0.125f * LOG2E;   // fold 1/sqrt(D) and the exp2 domain scale into q
#pragma unroll
  for (int mi = 0; mi < 8; ++mi) {
    const int m = row0 + wm * 128 + mi * 16 + quad * 4;   // C row = quad*4+r
    const int bb = m >> 8;
    const int s0 = m & 255;   // multiple of 4; +r stays in-window
#pragma unroll
    for (int nj = 0; nj < 4; ++nj) {
      const int n = col0 + wn * 64 + nj * 16 + l15;       // C col = lane&15
      const int hn = (n >> 6) & 15;
      const int dd2 = n & 63;
      const float bv = bias[n];
      if (which == 0) {
        size_t base = ((size_t)(bb * HH + hn) * SS + s0) * DD + dd2;
#pragma unroll
        for (int r = 0; r < 4; ++r)
          q[base + (size_t)r * DD] = f2bf((acc[mi][nj][r] + bv) * QS);
      } else if (which == 1) {
        size_t base = ((size_t)(bb * HH + hn) * SS + s0) * DD + dd2;
#pragma unroll
        for (int r = 0; r < 4; ++r)
          kx[base + (size_t)r * DD] = f2bf(acc[mi][nj][r] + bv);
      } else {
        // fragment-native v^T: kk = s0>>5, qv = (s0>>3)&3, e0 = s0&7 (0 or 4)
        const int kk = s0 >> 5, qv = (s0 >> 3) & 3, e0 = s0 & 7;
        const int nt = dd2 >> 4, lv = dd2 & 15;
        size_t base = (size_t)(bb * HH + hn) * 16384 +
                      (size_t)((kk * 4 + nt) * 64 + qv * 16 + lv) * 8 + e0;
        ushort4 pk;   // r=0..3 -> consecutive e -> contiguous 8B (8B-aligned)
        pk.x = f2bf(acc[mi][nj][0] + bv);
        pk.y = f2bf(acc[mi][nj][1] + bv);
        pk.z = f2bf(acc[mi][nj][2] + bv);
        pk.w = f2bf(acc[mi][nj][3] + bv);
        *(ushort4*)(vt + base) = pk;
      }
    }
  }
}

// ---------------- attention: one block per (b,h), 4 q-blocks looped ----------------
__global__ __launch_bounds__(256) void attn_kernel(const unsigned short* __restrict__ q,
                                                   const unsigned short* __restrict__ kx,
                                                   const unsigned short* __restrict__ vt,
                                                   const float* __restrict__ biasC,
                                                   unsigned short* __restrict__ ctx) {
  __shared__ unsigned short Ks[256 * 64];   // 32KB, swizzled: chunk c at c^(row&7)
  __shared__ unsigned short P[4][16 * 256]; // 32KB, per-wave slices, swizzled
  const int tid = threadIdx.x;
  const int wave = tid >> 6, lane = tid & 63;
  const int l15 = lane & 15, quad = lane >> 4;
  const int swl = l15 & 7;
  const int bh = blockIdx.x;
  const int h = bh & 15;
  const int b_ = bh >> 4;
  const unsigned short* qp = q + (size_t)bh * SS * DD;
  const unsigned short* kp = kx + (size_t)bh * SS * DD;
  const unsigned short* vp = vt + (size_t)bh * SS * DD;   // fragment-native layout

#pragma unroll
  for (int rr = 0; rr < 8; ++rr) {
    int gc = rr * 256 + tid;
    int row = gc >> 3, sc = gc & 7;
    int c = sc ^ (row & 7);
    gld16(kp + row * 64 + c * 8, Ks + (rr * 256 + wave * 64) * 8);
  }
  __syncthreads();

  unsigned short* Pw = &P[wave][0];
  for (int qblk = 0; qblk < 4; ++qblk) {
    const int qr0 = qblk * 64 + wave * 16;
    bf16x8 aq0 = *(const bf16x8*)(qp + (qr0 + l15) * DD + quad * 8);
    bf16x8 aq1 = *(const bf16x8*)(qp + (qr0 + l15) * DD + 32 + quad * 8);

    f32x4 sacc[16];
#pragma unroll
    for (int j = 0; j < 16; ++j) sacc[j] = (f32x4){0.f, 0.f, 0.f, 0.f};
#pragma unroll
    for (int j = 0; j < 16; ++j) {
      const unsigned short* krow = Ks + (j * 16 + l15) * 64;
      bf16x8 b0 = *(const bf16x8*)(krow + (quad ^ swl) * 8);
      bf16x8 b1 = *(const bf16x8*)(krow + ((4 + quad) ^ swl) * 8);
      sacc[j] = __builtin_amdgcn_mfma_f32_16x16x32_bf16(aq0, b0, sacc[j], 0, 0, 0);
      sacc[j] = __builtin_amdgcn_mfma_f32_16x16x32_bf16(aq1, b1, sacc[j], 0, 0, 0);
    }
#pragma unroll
    for (int r = 0; r < 4; ++r) {
      const int prow = quad * 4 + r;
      const float* bC = biasC + ((size_t)((h * 256 + qr0 + prow) * 16 + l15)) * 16;
      float4 bv0 = ((const float4*)bC)[0];
      float4 bv1 = ((const float4*)bC)[1];
      float4 bv2 = ((const float4*)bC)[2];
      float4 bv3 = ((const float4*)bC)[3];
      float bj[16] = {bv0.x, bv0.y, bv0.z, bv0.w, bv1.x, bv1.y, bv1.z, bv1.w,
                      bv2.x, bv2.y, bv2.z, bv2.w, bv3.x, bv3.y, bv3.z, bv3.w};
      float s = 0.f;
#pragma unroll
      for (int j = 0; j < 16; ++j) {
        float e = fast_exp2(sacc[j][r] + bj[j]);
        sacc[j][r] = e;
        s += e;
      }
#pragma unroll
      for (int m = 8; m >= 1; m >>= 1) s += __shfl_xor(s, m, 16);
      float rs = fast_rcp(s);
      const int psw = prow & 7;
#pragma unroll
      for (int j = 0; j < 16; ++j) {
        union { float f; unsigned int u; } cv; cv.f = sacc[j][r] * rs;
        unsigned short pb = (unsigned short)((cv.u + 0x8000u) >> 16);  // cheap RN
        Pw[prow * 256 + (((2 * j + (l15 >> 3)) ^ psw) << 3) + swl] = pb;
      }
    }
    f32x4 cacc[4];
#pragma unroll
    for (int nt = 0; nt < 4; ++nt) cacc[nt] = (f32x4){0.f, 0.f, 0.f, 0.f};
#pragma unroll
    for (int kk = 0; kk < 8; ++kk) {
      bf16x8 a = *(const bf16x8*)(Pw + l15 * 256 + (((kk * 4 + quad) ^ swl) << 3));
#pragma unroll
      for (int nt = 0; nt < 4; ++nt) {
        // fragment-native V^T: dense lane-linear 1KB load (was 64-line scatter)
        bf16x8 b = *(const bf16x8*)(vp + (size_t)(kk * 4 + nt) * 512 + lane * 8);
        cacc[nt] = __builtin_amdgcn_mfma_f32_16x16x32_bf16(a, b, cacc[nt], 0, 0, 0);
      }
    }
#pragma unroll
    for (int nt = 0; nt < 4; ++nt)
#pragma unroll
      for (int r = 0; r < 4; ++r)
        ctx[(size_t)(b_ * SS + qr0 + quad * 4 + r) * EE + h * DD + nt * 16 + l15] =
            f2bf(cacc[nt][r]);
  }
}

// ---------------- out projection: ctx_bf16 @ out_w^T + out_b -> fp32 ----------------
__global__ __launch_bounds__(512, 2) void out_gemm(const unsigned short* __restrict__ A,
                                                   const unsigned short* __restrict__ Bw,
                                                   const float* __restrict__ bias,
                                                   float* __restrict__ out) {
  __shared__ unsigned short S_A[32768];
  __shared__ unsigned short S_B[32768];
  const int bid = blockIdx.x;
  const int xcd = bid & 7, j = bid >> 3;          // 64 blocks per XCD
  const int row0 = (xcd * 16 + (j & 15)) * 256;   // XCD-private row band
  const int col0 = (j >> 4) * 256;                // 4 col panels
  const int tid = threadIdx.x;
  const int wave = tid >> 6, lane = tid & 63;
  const int wm = wave >> 2, wn = wave & 3;
  const int l15 = lane & 15, quad = lane >> 4;
  f32x4 acc[8][4];
#pragma unroll
  for (int i = 0; i < 8; ++i)
#pragma unroll
    for (int j2 = 0; j2 < 4; ++j2) acc[i][j2] = (f32x4){0.f, 0.f, 0.f, 0.f};
  gemm256_loop(A, Bw, S_A, S_B, row0, col0, acc);
#pragma unroll
  for (int mi = 0; mi < 8; ++mi) {
    const int m0 = row0 + wm * 128 + mi * 16 + quad * 4;
#pragma unroll
    for (int nj = 0; nj < 4; ++nj) {
      const int n = col0 + wn * 64 + nj * 16 + l15;
      const float bv = bias[n];
#pragma unroll
      for (int r = 0; r < 4; ++r)
        out[(size_t)(m0 + r) * EE + n] = acc[mi][nj][r] + bv;
    }
  }
}

// ---------------- workspace layout (bytes) ----------------
#define WS_XCTX  ((size_t)0)
#define WS_QKVW  ((size_t)67108864)
#define WS_OUTW  ((size_t)73400320)
#define WS_BIAS  ((size_t)75497472)
#define WS_Q     ((size_t)79691776)
#define WS_K     ((size_t)146800640)
#define WS_VT    ((size_t)213909504)
// total required: 281,018,368 bytes

extern "C" void kernel_launch(void* const* d_in, const int* in_sizes, int n_in,
                              void* d_out, int out_size, void* d_ws, size_t ws_size,
                              hipStream_t stream) {
  (void)in_sizes; (void)n_in; (void)out_size; (void)ws_size;
  const float* x      = (const float*)d_in[0];
  const float* qkv_w  = (const float*)d_in[1];
  const float* qkv_b  = (const float*)d_in[2];
  const float* out_w  = (const float*)d_in[3];
  const float* out_b  = (const float*)d_in[4];
  const float* btab   = (const float*)d_in[5];
  const int*   ridx   = (const int*)d_in[6];
  float* out = (float*)d_out;
  char* ws = (char*)d_ws;

  unsigned short* xctx  = (unsigned short*)(ws + WS_XCTX);
  unsigned short* qkvwb = (unsigned short*)(ws + WS_QKVW);
  unsigned short* outwb = (unsigned short*)(ws + WS_OUTW);
  float*          biasC = (float*)(ws + WS_BIAS);
  unsigned short* q     = (unsigned short*)(ws + WS_Q);
  unsigned short* k     = (unsigned short*)(ws + WS_K);
  unsigned short* vt    = (unsigned short*)(ws + WS_VT);

  prep_kernel<<<8192, 256, 0, stream>>>((const float4*)x, (const float4*)qkv_w,
                                        (const float4*)out_w, btab, ridx,
                                        (ushort4*)xctx, (ushort4*)qkvwb,
                                        (ushort4*)outwb, biasC);
  qkv_gemm<<<dim3((MM / 256) * ((3 * EE) / 256)), 512, 0, stream>>>(xctx, qkvwb, qkv_b,
                                                                    q, k, vt);
  attn_kernel<<<BB * HH, 256, 0, stream>>>(q, k, vt, biasC, xctx);
  out_gemm<<<dim3((MM / 256) * (EE / 256)), 512, 0, stream>>>(xctx, outwb, out_b, out);
}